// Round 1
// baseline (3042.334 us; speedup 1.0000x reference)
//
#include <hip/hip_runtime.h>
#include <hip/hip_bf16.h>
#include <math.h>

// Problem constants
#define B_   256
#define HID_ 1024
#define SP_  2048
#define N_   196        // 14*14
#define NJ_  (B_ * N_)  // 50176 = 784 * 64
#define SPB_ (SP_ * N_) // 401408 elems per batch of spatial

// ---------------------------------------------------------------------------
// K1: h1[b,d] = sum_h hidden[b,h] * W1[h,d] + b1[d]     (256x1024 @ 1024x1024)
// Block: 256 threads handle 256 d's for 8 consecutive b's (W1h reuse x8).
// ---------------------------------------------------------------------------
__global__ __launch_bounds__(256) void k1_h1(
    const float* __restrict__ hidden, const float* __restrict__ W1,
    const float* __restrict__ b1, float* __restrict__ h1)
{
    __shared__ float hs[8][HID_];
    const int t = threadIdx.x;
    const int d = blockIdx.x * 256 + t;   // grid.x = 4
    const int b0 = blockIdx.y * 8;        // grid.y = 32

    for (int i = t; i < 8 * HID_; i += 256)
        hs[i >> 10][i & 1023] = hidden[(size_t)(b0 + (i >> 10)) * HID_ + (i & 1023)];
    __syncthreads();

    float acc[8] = {0.f,0.f,0.f,0.f,0.f,0.f,0.f,0.f};
    for (int h = 0; h < HID_; ++h) {
        const float w = W1[(size_t)h * HID_ + d];
#pragma unroll
        for (int i = 0; i < 8; ++i) acc[i] += hs[i][h] * w;
    }
    const float bias = b1[d];
#pragma unroll
    for (int i = 0; i < 8; ++i)
        h1[(size_t)(b0 + i) * HID_ + d] = acc[i] + bias;
}

// ---------------------------------------------------------------------------
// K2: the big GEMM, transposed + batch-flattened:
//   C[d, j] = sum_c W1s^T[d,c] * spT[c,j],  j = b*196 + n  (M=1024,N=50176,K=2048)
//   A[d,c] = W1[(1024+c)*1024 + d]   (contiguous in d)
//   B[c,j] = spatial[b*401408 + c*196 + n]  (contiguous in j within batch)
// Fused epilogue: pre = C + h1[b,d]; partial_score = sum_d tanh(pre)*w2[d]
// written per d-tile (deterministic, no atomics): ps[dt*NJ + j].
// Tile 64(d) x 64(j), KT=32, 256 threads, 4x4 accs/thread.
// ---------------------------------------------------------------------------
__global__ __launch_bounds__(256) void k2_gemm_scores(
    const float* __restrict__ spatial, const float* __restrict__ W1,
    const float* __restrict__ W2, const float* __restrict__ h1,
    float* __restrict__ ps)
{
    __shared__ float As[32][64];  // As[k][dd]
    __shared__ float Bs[32][64];  // Bs[k][jj]

    const int t  = threadIdx.x;
    const int d0 = blockIdx.x * 64;   // grid.x = 16  (d tiles; consecutive blocks share B panel)
    const int j0 = blockIdx.y * 64;   // grid.y = 784

    // cooperative-load lane mapping
    const int ld = t & 63;   // element within row of 64
    const int lk = t >> 6;   // 0..3 (k offset base)

    // A source: fixed d = d0+ld, walk c
    const float* Aptr = W1 + (size_t)(HID_ + lk) * HID_ + (d0 + ld);
    // B source: fixed j = j0+ld, walk c
    const int j  = j0 + ld;
    const int bb = j / N_;
    const int nn = j - bb * N_;
    const float* Bptr = spatial + (size_t)bb * SPB_ + (size_t)lk * N_ + nn;

    // compute-thread mapping: 16x16 grid, 4x4 outputs each
    const int tr = t >> 4;   // d direction
    const int tc = t & 15;   // j direction

    float acc[4][4] = {};

    for (int c0 = 0; c0 < SP_; c0 += 32) {
#pragma unroll
        for (int i = 0; i < 8; ++i) {
            As[lk + 4 * i][ld] = Aptr[(size_t)(c0 + 4 * i) * HID_];
            Bs[lk + 4 * i][ld] = Bptr[(size_t)(c0 + 4 * i) * N_];
        }
        __syncthreads();
#pragma unroll
        for (int k = 0; k < 32; ++k) {
            float av[4], bv[4];
            *(float4*)av = *(const float4*)&As[k][tr * 4];
            *(float4*)bv = *(const float4*)&Bs[k][tc * 4];
#pragma unroll
            for (int di = 0; di < 4; ++di)
#pragma unroll
                for (int ji = 0; ji < 4; ++ji)
                    acc[di][ji] += av[di] * bv[ji];
        }
        __syncthreads();
    }

    // epilogue: pre = acc + h1[bj,d]; partial[ji] = sum_di tanh(pre)*w2[d]
    float w2v[4];
#pragma unroll
    for (int di = 0; di < 4; ++di) w2v[di] = W2[d0 + tr * 4 + di];

    float partial[4] = {0.f, 0.f, 0.f, 0.f};
#pragma unroll
    for (int ji = 0; ji < 4; ++ji) {
        const int jg = j0 + tc * 4 + ji;
        const int bj = jg / N_;
        const float* h1row = h1 + (size_t)bj * HID_ + d0 + tr * 4;
#pragma unroll
        for (int di = 0; di < 4; ++di) {
            const float pre = acc[di][ji] + h1row[di];
            partial[ji] += tanhf(pre) * w2v[di];
        }
    }

    // block reduce over the 16 tr-threads per j column (LDS atomics, in-block)
    __shared__ float red[64];
    if (t < 64) red[t] = 0.f;
    __syncthreads();
#pragma unroll
    for (int ji = 0; ji < 4; ++ji)
        atomicAdd(&red[tc * 4 + ji], partial[ji]);
    __syncthreads();
    if (t < 64)
        ps[(size_t)blockIdx.x * NJ_ + j0 + t] = red[t];
}

// ---------------------------------------------------------------------------
// K3: scores[b,n] = sum_dt ps[dt, b*196+n]; attn = softmax_n(scores)
// (b2 dropped: softmax is shift-invariant.)  One block per b.
// ---------------------------------------------------------------------------
__global__ __launch_bounds__(256) void k3_softmax(
    const float* __restrict__ ps, float* __restrict__ attn)
{
    const int b = blockIdx.x;
    const int t = threadIdx.x;
    __shared__ float sdata[256];

    float s = -1e30f;
    if (t < N_) {
        s = 0.f;
        for (int dt = 0; dt < 16; ++dt)
            s += ps[(size_t)dt * NJ_ + b * N_ + t];
    }
    sdata[t] = s;
    __syncthreads();
    for (int off = 128; off > 0; off >>= 1) {
        if (t < off) sdata[t] = fmaxf(sdata[t], sdata[t + off]);
        __syncthreads();
    }
    const float m = sdata[0];
    __syncthreads();
    const float e = (t < N_) ? expf(s - m) : 0.f;
    sdata[t] = e;
    __syncthreads();
    for (int off = 128; off > 0; off >>= 1) {
        if (t < off) sdata[t] += sdata[t + off];
        __syncthreads();
    }
    const float inv = 1.f / sdata[0];
    if (t < N_) attn[(size_t)b * N_ + t] = e * inv;
}

// ---------------------------------------------------------------------------
// K4: context[b,c] = sum_n attn[b,n] * spatial[b, c*196 + n]
// One wave per (b,c); lanes stride n; shuffle reduce.
// ---------------------------------------------------------------------------
__global__ __launch_bounds__(256) void k4_context(
    const float* __restrict__ spatial, const float* __restrict__ attn,
    float* __restrict__ ctx)
{
    const int wid  = (blockIdx.x * 256 + threadIdx.x) >> 6;  // global wave id
    const int lane = threadIdx.x & 63;
    const int b = wid >> 11;      // / 2048
    const int c = wid & 2047;
    const float* sp = spatial + (size_t)b * SPB_ + (size_t)c * N_;
    const float* at = attn + (size_t)b * N_;

    float sum = 0.f;
    for (int n = lane; n < N_; n += 64)
        sum += at[n] * sp[n];
#pragma unroll
    for (int off = 32; off > 0; off >>= 1)
        sum += __shfl_down(sum, off, 64);
    if (lane == 0)
        ctx[(size_t)b * 2048 + c] = sum;
}

// ---------------------------------------------------------------------------
extern "C" void kernel_launch(void* const* d_in, const int* in_sizes, int n_in,
                              void* d_out, int out_size, void* d_ws, size_t ws_size,
                              hipStream_t stream)
{
    const float* hidden  = (const float*)d_in[0];
    const float* spatial = (const float*)d_in[1];
    const float* W1      = (const float*)d_in[2];
    const float* b1      = (const float*)d_in[3];
    const float* W2      = (const float*)d_in[4];
    // b2 (d_in[5]) unused: softmax is shift-invariant.

    float* out_ctx  = (float*)d_out;                     // 256*2048
    float* out_attn = (float*)d_out + (size_t)B_ * 2048; // 256*196

    char* ws = (char*)d_ws;
    float* h1 = (float*)ws;                         // 256*1024*4 = 1 MB
    float* psb = (float*)(ws + (1 << 20));          // 16*50176*4 = 3.06 MB

    k1_h1<<<dim3(4, 32), 256, 0, stream>>>(hidden, W1, b1, h1);
    k2_gemm_scores<<<dim3(16, 784), 256, 0, stream>>>(spatial, W1, W2, h1, psb);
    k3_softmax<<<dim3(B_), 256, 0, stream>>>(psb, out_attn);
    k4_context<<<dim3((B_ * 2048) / 4), 256, 0, stream>>>(spatial, out_attn, out_ctx);
}

// Round 2
// 1158.678 us; speedup vs baseline: 2.6257x; 2.6257x over previous
//
#include <hip/hip_runtime.h>
#include <hip/hip_bf16.h>
#include <math.h>

// Problem constants
#define B_   256
#define HID_ 1024
#define SP_  2048
#define N_   196        // 14*14
#define NJ_  (B_ * N_)  // 50176 = 392 * 128
#define SPB_ (SP_ * N_) // elems per batch of spatial

typedef float  f32x4  __attribute__((ext_vector_type(4)));
typedef short  s16x8  __attribute__((ext_vector_type(8)));

#define GLOBAL_AS(p) ((const __attribute__((address_space(1))) void*)(p))
#define LDS_AS(p)    ((__attribute__((address_space(3))) void*)(p))

// ---------------------------------------------------------------------------
// K1: h1[b,d] = hidden @ W1h + b1   (256x1024 @ 1024x1024)
// ---------------------------------------------------------------------------
__global__ __launch_bounds__(256) void k1_h1(
    const float* __restrict__ hidden, const float* __restrict__ W1,
    const float* __restrict__ b1, float* __restrict__ h1)
{
    __shared__ float hs[8][HID_];
    const int t = threadIdx.x;
    const int d = blockIdx.x * 256 + t;
    const int b0 = blockIdx.y * 8;

    for (int i = t; i < 8 * HID_; i += 256)
        hs[i >> 10][i & 1023] = hidden[(size_t)(b0 + (i >> 10)) * HID_ + (i & 1023)];
    __syncthreads();

    float acc[8] = {};
    for (int h = 0; h < HID_; ++h) {
        const float w = W1[(size_t)h * HID_ + d];
#pragma unroll
        for (int i = 0; i < 8; ++i) acc[i] += hs[i][h] * w;
    }
    const float bias = b1[d];
#pragma unroll
    for (int i = 0; i < 8; ++i)
        h1[(size_t)(b0 + i) * HID_ + d] = acc[i] + bias;
}

// ---------------------------------------------------------------------------
// K0a: pack A = W1s^T (d x c, 1024x2048) into hi/lo bf16 tiles.
// Tile (dt, cs): 128 d x 32 c, layout [cg(4)][dd(128)][c8(8)], 4096 elems.
// Global order: [dt(8)][cs(64)][tile 4096]
// ---------------------------------------------------------------------------
__global__ __launch_bounds__(256) void k0a_packA(
    const float* __restrict__ W1, __hip_bfloat16* __restrict__ Ah,
    __hip_bfloat16* __restrict__ Al)
{
    const size_t idx = (size_t)blockIdx.x * 256 + threadIdx.x;  // < 2,097,152
    const int dt = idx >> 18;
    const int cs = (idx >> 12) & 63;
    const int e  = idx & 4095;
    const int cg = e >> 10, dd = (e >> 3) & 127, c8 = e & 7;
    const int d = dt * 128 + dd;
    const int c = cs * 32 + cg * 8 + c8;
    const float v = W1[(size_t)(HID_ + c) * HID_ + d];
    const __hip_bfloat16 hi = __float2bfloat16(v);
    Ah[idx] = hi;
    Al[idx] = __float2bfloat16(v - __bfloat162float(hi));
}

// ---------------------------------------------------------------------------
// K0b: pack B = spT (c x j, 2048 x 50176) into hi/lo bf16 tiles.
// Tile (jt, cs): 32 c x 128 j, layout [cg(4)][jj(128)][c8(8)], 4096 elems.
// Global order: [jt(392)][cs(64)][tile 4096].  One block per tile.
// ---------------------------------------------------------------------------
__global__ __launch_bounds__(256) void k0b_packB(
    const float* __restrict__ spatial, __hip_bfloat16* __restrict__ Bh,
    __hip_bfloat16* __restrict__ Bl)
{
    __shared__ float tf[32][128];
    const int jt = blockIdx.x, cs = blockIdx.y;
    const int tid = threadIdx.x;
    const int ji = tid & 127, c2 = tid >> 7;

    const int j = jt * 128 + ji;
    const int b = j / N_, n = j - b * N_;
    const float* sp = spatial + (size_t)b * SPB_ + n;
#pragma unroll
    for (int ci = c2; ci < 32; ci += 2)
        tf[ci][ji] = sp[(size_t)(cs * 32 + ci) * N_];
    __syncthreads();

    const size_t base = ((size_t)jt * 64 + cs) * 4096;
#pragma unroll
    for (int i = 0; i < 16; ++i) {
        const int e = tid * 16 + i;
        const int cg = e >> 10, jj = (e >> 3) & 127, c8 = e & 7;
        const float v = tf[cg * 8 + c8][jj];
        const __hip_bfloat16 hi = __float2bfloat16(v);
        Bh[base + e] = hi;
        Bl[base + e] = __float2bfloat16(v - __bfloat162float(hi));
    }
}

// ---------------------------------------------------------------------------
// K2 (MFMA): C[d,j] = A·B via 3-pass bf16 split; fused epilogue
//   partial_score[dt, j] = sum_{d in tile} tanh(C + h1[bj,d]) * w2[d]
// 128x128 tile, BK=32, 4 waves (2d x 2j), 16x16x32 MFMA, 4x4 frags/wave.
// ---------------------------------------------------------------------------
__global__ __launch_bounds__(256) void k2_mfma(
    const __hip_bfloat16* __restrict__ Ah, const __hip_bfloat16* __restrict__ Al,
    const __hip_bfloat16* __restrict__ Bh, const __hip_bfloat16* __restrict__ Bl,
    const float* __restrict__ W2, const float* __restrict__ h1,
    float* __restrict__ ps)
{
    __shared__ __align__(16) short lds[4][4096];  // Ah,Al,Bh,Bl tiles (8 KB each)

    const int tid = threadIdx.x;
    const int l = tid & 63;
    const int w = tid >> 6;           // wave 0..3
    const int wd = w >> 1, wj = w & 1;
    const int cg = l >> 4, r = l & 15;

    // XCD-chunked swizzle: 3136 blocks, 8 XCDs, dt fastest within chunk.
    const int f = blockIdx.x;
    const int xcd = f & 7, p = f >> 3;
    const int dt = p & 7;             // 0..7
    const int jt = xcd * 49 + (p >> 3); // 0..391

    // wave w stages buffer w (A_hi, A_lo, B_hi, B_lo)
    const size_t tileA = ((size_t)dt * 64) * 4096;
    const size_t tileB = ((size_t)jt * 64) * 4096;
    const __hip_bfloat16* src_base =
        (w == 0) ? Ah + tileA : (w == 1) ? Al + tileA :
        (w == 2) ? Bh + tileB : Bl + tileB;
    short* ldsb = &lds[w][0];

    f32x4 acc[4][4] = {};

    for (int cs = 0; cs < 64; ++cs) {
        const __hip_bfloat16* s = src_base + (size_t)cs * 4096 + l * 8;
#pragma unroll
        for (int li = 0; li < 8; ++li) {
            __builtin_amdgcn_global_load_lds(GLOBAL_AS(s + li * 512),
                                             LDS_AS(ldsb + li * 512), 16, 0, 0);
        }
        __syncthreads();

        s16x8 a_h[4], a_l[4], b_h[4], b_l[4];
#pragma unroll
        for (int mi = 0; mi < 4; ++mi) {
            const int dd = wd * 64 + mi * 16 + r;
            a_h[mi] = *(const s16x8*)&lds[0][(cg * 128 + dd) * 8];
            a_l[mi] = *(const s16x8*)&lds[1][(cg * 128 + dd) * 8];
        }
#pragma unroll
        for (int ni = 0; ni < 4; ++ni) {
            const int jj = wj * 64 + ni * 16 + r;
            b_h[ni] = *(const s16x8*)&lds[2][(cg * 128 + jj) * 8];
            b_l[ni] = *(const s16x8*)&lds[3][(cg * 128 + jj) * 8];
        }
#pragma unroll
        for (int mi = 0; mi < 4; ++mi)
#pragma unroll
            for (int ni = 0; ni < 4; ++ni) {
                acc[mi][ni] = __builtin_amdgcn_mfma_f32_16x16x32_bf16(
                    a_h[mi], b_h[ni], acc[mi][ni], 0, 0, 0);
                acc[mi][ni] = __builtin_amdgcn_mfma_f32_16x16x32_bf16(
                    a_h[mi], b_l[ni], acc[mi][ni], 0, 0, 0);
                acc[mi][ni] = __builtin_amdgcn_mfma_f32_16x16x32_bf16(
                    a_l[mi], b_h[ni], acc[mi][ni], 0, 0, 0);
            }
        __syncthreads();
    }

    // Epilogue: partial[j] = sum_d tanh(acc + h1) * w2
    const int q4 = cg * 4;
    float w2v[4][4];
#pragma unroll
    for (int mi = 0; mi < 4; ++mi)
#pragma unroll
        for (int q = 0; q < 4; ++q)
            w2v[mi][q] = W2[dt * 128 + wd * 64 + mi * 16 + q4 + q];

    float partial[4];
#pragma unroll
    for (int ni = 0; ni < 4; ++ni) {
        const int jg = jt * 128 + wj * 64 + ni * 16 + r;
        const int bj = jg / N_;
        const float* h1p = h1 + (size_t)bj * HID_ + dt * 128 + wd * 64;
        float s = 0.f;
#pragma unroll
        for (int mi = 0; mi < 4; ++mi)
#pragma unroll
            for (int q = 0; q < 4; ++q)
                s += tanhf(acc[mi][ni][q] + h1p[mi * 16 + q4 + q]) * w2v[mi][q];
        partial[ni] = s;
    }

    float* red = (float*)&lds[0][0];
    if (tid < 128) red[tid] = 0.f;
    __syncthreads();
#pragma unroll
    for (int ni = 0; ni < 4; ++ni)
        atomicAdd(&red[wj * 64 + ni * 16 + r], partial[ni]);
    __syncthreads();
    if (tid < 128)
        ps[(size_t)dt * NJ_ + (size_t)jt * 128 + tid] = red[tid];
}

// ---------------------------------------------------------------------------
// K2 fallback (fp32 vector path) if workspace is too small for packing.
// ---------------------------------------------------------------------------
__global__ __launch_bounds__(256) void k2_fb(
    const float* __restrict__ spatial, const float* __restrict__ W1,
    const float* __restrict__ W2, const float* __restrict__ h1,
    float* __restrict__ ps)
{
    __shared__ float As[32][64];
    __shared__ float Bs[32][64];
    const int t = threadIdx.x;
    const int d0 = blockIdx.x * 64;
    const int j0 = blockIdx.y * 64;
    const int ld = t & 63, lk = t >> 6;
    const float* Aptr = W1 + (size_t)(HID_ + lk) * HID_ + (d0 + ld);
    const int j = j0 + ld;
    const int bb = j / N_, nn = j - bb * N_;
    const float* Bptr = spatial + (size_t)bb * SPB_ + (size_t)lk * N_ + nn;
    const int tr = t >> 4, tc = t & 15;
    float acc[4][4] = {};
    for (int c0 = 0; c0 < SP_; c0 += 32) {
#pragma unroll
        for (int i = 0; i < 8; ++i) {
            As[lk + 4 * i][ld] = Aptr[(size_t)(c0 + 4 * i) * HID_];
            Bs[lk + 4 * i][ld] = Bptr[(size_t)(c0 + 4 * i) * N_];
        }
        __syncthreads();
#pragma unroll
        for (int k = 0; k < 32; ++k) {
            float av[4], bv[4];
            *(float4*)av = *(const float4*)&As[k][tr * 4];
            *(float4*)bv = *(const float4*)&Bs[k][tc * 4];
#pragma unroll
            for (int di = 0; di < 4; ++di)
#pragma unroll
                for (int ji = 0; ji < 4; ++ji)
                    acc[di][ji] += av[di] * bv[ji];
        }
        __syncthreads();
    }
    float w2v[4];
#pragma unroll
    for (int di = 0; di < 4; ++di) w2v[di] = W2[d0 + tr * 4 + di];
    float partial[4] = {};
#pragma unroll
    for (int ji = 0; ji < 4; ++ji) {
        const int jg = j0 + tc * 4 + ji;
        const int bj = jg / N_;
        const float* h1row = h1 + (size_t)bj * HID_ + d0 + tr * 4;
#pragma unroll
        for (int di = 0; di < 4; ++di)
            partial[ji] += tanhf(acc[di][ji] + h1row[di]) * w2v[di];
    }
    __shared__ float red[64];
    if (t < 64) red[t] = 0.f;
    __syncthreads();
#pragma unroll
    for (int ji = 0; ji < 4; ++ji)
        atomicAdd(&red[tc * 4 + ji], partial[ji]);
    __syncthreads();
    if (t < 64)
        ps[(size_t)blockIdx.x * NJ_ + j0 + t] = red[t];
}

// ---------------------------------------------------------------------------
// K3: scores[b,n] = sum_slices ps; attn = softmax_n  (b2 shift-invariant)
// ---------------------------------------------------------------------------
__global__ __launch_bounds__(256) void k3_softmax(
    const float* __restrict__ ps, float* __restrict__ attn, int nslices)
{
    const int b = blockIdx.x;
    const int t = threadIdx.x;
    __shared__ float sdata[256];

    float s = -1e30f;
    if (t < N_) {
        s = 0.f;
        for (int dt = 0; dt < nslices; ++dt)
            s += ps[(size_t)dt * NJ_ + b * N_ + t];
    }
    sdata[t] = s;
    __syncthreads();
    for (int off = 128; off > 0; off >>= 1) {
        if (t < off) sdata[t] = fmaxf(sdata[t], sdata[t + off]);
        __syncthreads();
    }
    const float m = sdata[0];
    __syncthreads();
    const float e = (t < N_) ? expf(s - m) : 0.f;
    sdata[t] = e;
    __syncthreads();
    for (int off = 128; off > 0; off >>= 1) {
        if (t < off) sdata[t] += sdata[t + off];
        __syncthreads();
    }
    const float inv = 1.f / sdata[0];
    if (t < N_) attn[(size_t)b * N_ + t] = e * inv;
}

// ---------------------------------------------------------------------------
// K4: context[b,c] = sum_n attn[b,n] * spatial[b, c*196 + n]
// ---------------------------------------------------------------------------
__global__ __launch_bounds__(256) void k4_context(
    const float* __restrict__ spatial, const float* __restrict__ attn,
    float* __restrict__ ctx)
{
    const int wid = (blockIdx.x * 256 + threadIdx.x) >> 6;
    const int lane = threadIdx.x & 63;
    const int b = wid >> 11;
    const int c = wid & 2047;
    const float* sp = spatial + (size_t)b * SPB_ + (size_t)c * N_;
    const float* at = attn + (size_t)b * N_;

    float sum = 0.f;
    for (int n = lane; n < N_; n += 64)
        sum += at[n] * sp[n];
#pragma unroll
    for (int off = 32; off > 0; off >>= 1)
        sum += __shfl_down(sum, off, 64);
    if (lane == 0)
        ctx[(size_t)b * 2048 + c] = sum;
}

// ---------------------------------------------------------------------------
extern "C" void kernel_launch(void* const* d_in, const int* in_sizes, int n_in,
                              void* d_out, int out_size, void* d_ws, size_t ws_size,
                              hipStream_t stream)
{
    const float* hidden  = (const float*)d_in[0];
    const float* spatial = (const float*)d_in[1];
    const float* W1      = (const float*)d_in[2];
    const float* b1      = (const float*)d_in[3];
    const float* W2      = (const float*)d_in[4];
    // b2 unused: softmax shift-invariant.

    float* out_ctx  = (float*)d_out;
    float* out_attn = (float*)d_out + (size_t)B_ * 2048;

    char* ws = (char*)d_ws;
    float* h1 = (float*)ws;                               // 1 MB
    float* psb = (float*)(ws + (1u << 20));               // up to 16 slices (3.2 MB)

    // MFMA-path workspace layout
    const size_t offAh = 4u << 20;                         // 4 MB
    const size_t offAl = 8u << 20;                         // 4 MB
    const size_t offBh = 12u << 20;                        // 196 MB
    const size_t szB   = (size_t)392 * 64 * 4096 * 2;      // 205,520,896 B
    const size_t offBl = offBh + szB;
    const size_t needed = offBl + szB;                     // ~404 MB

    k1_h1<<<dim3(4, 32), 256, 0, stream>>>(hidden, W1, b1, h1);

    if (ws_size >= needed) {
        __hip_bfloat16* Ah = (__hip_bfloat16*)(ws + offAh);
        __hip_bfloat16* Al = (__hip_bfloat16*)(ws + offAl);
        __hip_bfloat16* Bh = (__hip_bfloat16*)(ws + offBh);
        __hip_bfloat16* Bl = (__hip_bfloat16*)(ws + offBl);

        k0a_packA<<<dim3(8192), 256, 0, stream>>>(W1, Ah, Al);
        k0b_packB<<<dim3(392, 64), 256, 0, stream>>>(spatial, Bh, Bl);
        k2_mfma<<<dim3(3136), 256, 0, stream>>>(Ah, Al, Bh, Bl, W2, h1, psb);
        k3_softmax<<<dim3(B_), 256, 0, stream>>>(psb, out_attn, 8);
    } else {
        k2_fb<<<dim3(16, 784), 256, 0, stream>>>(spatial, W1, W2, h1, psb);
        k3_softmax<<<dim3(B_), 256, 0, stream>>>(psb, out_attn, 16);
    }
    k4_context<<<dim3((B_ * 2048) / 4), 256, 0, stream>>>(spatial, out_attn, out_ctx);
}

// Round 3
// 710.781 us; speedup vs baseline: 4.2803x; 1.6301x over previous
//
#include <hip/hip_runtime.h>
#include <hip/hip_bf16.h>
#include <hip/hip_fp16.h>
#include <math.h>

// Problem constants
#define B_   256
#define HID_ 1024
#define SP_  2048
#define N_   196        // 14*14
#define NJ_  (B_ * N_)  // 50176 = 392 * 128
#define SPB_ (SP_ * N_) // elems per batch of spatial

typedef float    f32x4 __attribute__((ext_vector_type(4)));
typedef _Float16 f16x8 __attribute__((ext_vector_type(8)));

#define GLOBAL_AS(p) ((const __attribute__((address_space(1))) void*)(p))
#define LDS_AS(p)    ((__attribute__((address_space(3))) void*)(p))

// ---------------------------------------------------------------------------
// K1: h1[b,d] = hidden @ W1h + b1   (256x1024 @ 1024x1024)
// ---------------------------------------------------------------------------
__global__ __launch_bounds__(256) void k1_h1(
    const float* __restrict__ hidden, const float* __restrict__ W1,
    const float* __restrict__ b1, float* __restrict__ h1)
{
    __shared__ float hs[8][HID_];
    const int t = threadIdx.x;
    const int d = blockIdx.x * 256 + t;
    const int b0 = blockIdx.y * 8;

    for (int i = t; i < 8 * HID_; i += 256)
        hs[i >> 10][i & 1023] = hidden[(size_t)(b0 + (i >> 10)) * HID_ + (i & 1023)];
    __syncthreads();

    float acc[8] = {};
    for (int h = 0; h < HID_; ++h) {
        const float w = W1[(size_t)h * HID_ + d];
#pragma unroll
        for (int i = 0; i < 8; ++i) acc[i] += hs[i][h] * w;
    }
    const float bias = b1[d];
#pragma unroll
    for (int i = 0; i < 8; ++i)
        h1[(size_t)(b0 + i) * HID_ + d] = acc[i] + bias;
}

// ---------------------------------------------------------------------------
// K0a: pack A = W1s^T (d x c, 1024x2048) into fp16 tiles.
// Tile (dt, cs): 128 d x 32 c, layout [cg(4)][dd(128)][c8(8)], 4096 elems.
// Global order: [dt(8)][cs(64)][tile 4096]
// ---------------------------------------------------------------------------
__global__ __launch_bounds__(256) void k0a_packA(
    const float* __restrict__ W1, __half* __restrict__ Ah)
{
    const size_t idx = (size_t)blockIdx.x * 256 + threadIdx.x;  // < 2,097,152
    const int dt = idx >> 18;
    const int cs = (idx >> 12) & 63;
    const int e  = idx & 4095;
    const int cg = e >> 10, dd = (e >> 3) & 127, c8 = e & 7;
    const int d = dt * 128 + dd;
    const int c = cs * 32 + cg * 8 + c8;
    Ah[idx] = __float2half(W1[(size_t)(HID_ + c) * HID_ + d]);
}

// ---------------------------------------------------------------------------
// K0b: pack B = spT (c x j, 2048 x 50176) into fp16 tiles.
// Tile (jt, cs): 32 c x 128 j, layout [cg(4)][jj(128)][c8(8)], 4096 elems.
// Global order: [jt(392)][cs(64)][tile 4096].  One block per tile.
// ---------------------------------------------------------------------------
__global__ __launch_bounds__(256) void k0b_packB(
    const float* __restrict__ spatial, __half* __restrict__ Bh)
{
    __shared__ float tf[32][128];
    const int jt = blockIdx.x, cs = blockIdx.y;
    const int tid = threadIdx.x;
    const int ji = tid & 127, c2 = tid >> 7;

    const int j = jt * 128 + ji;
    const int b = j / N_, n = j - b * N_;
    const float* sp = spatial + (size_t)b * SPB_ + n;
#pragma unroll
    for (int ci = c2; ci < 32; ci += 2)
        tf[ci][ji] = sp[(size_t)(cs * 32 + ci) * N_];
    __syncthreads();

    const size_t base = ((size_t)jt * 64 + cs) * 4096;
#pragma unroll
    for (int i = 0; i < 16; ++i) {
        const int e = tid * 16 + i;
        const int cg = e >> 10, jj = (e >> 3) & 127, c8 = e & 7;
        Bh[base + e] = __float2half(tf[cg * 8 + c8][jj]);
    }
}

// ---------------------------------------------------------------------------
// K2 (MFMA): C[d,j] = A·B single-pass fp16; fused epilogue
//   partial_score[dt, j] = sum_{d in tile} tanh(C + h1[bj,d]) * w2[d]
// 128x128 tile, BK=32, 4 waves (2d x 2j), 16x16x32 MFMA f16, 4x4 frags/wave.
// ---------------------------------------------------------------------------
__global__ __launch_bounds__(256, 4) void k2_mfma(
    const __half* __restrict__ Ah, const __half* __restrict__ Bh,
    const float* __restrict__ W2, const float* __restrict__ h1,
    float* __restrict__ ps)
{
    __shared__ __align__(16) short lds[2][4096];  // A,B tiles (8 KB each)

    const int tid = threadIdx.x;
    const int l = tid & 63;
    const int w = tid >> 6;           // wave 0..3
    const int wd = w >> 1, wj = w & 1;
    const int cg = l >> 4, r = l & 15;

    // XCD-chunked swizzle: 3136 blocks, 8 XCDs, dt fastest within chunk.
    const int f = blockIdx.x;
    const int xcd = f & 7, p = f >> 3;
    const int dt = p & 7;               // 0..7
    const int jt = xcd * 49 + (p >> 3); // 0..391

    // staging roles: buf = w>>1 (0:A, 1:B), half = w&1
    const int buf = w >> 1, half = w & 1;
    const __half* src_base =
        (buf == 0 ? Ah + ((size_t)dt * 64) * 4096 : Bh + ((size_t)jt * 64) * 4096)
        + half * 2048;
    short* ldsb = &lds[buf][half * 2048];

    f32x4 acc[4][4] = {};

    for (int cs = 0; cs < 64; ++cs) {
        const __half* s = src_base + (size_t)cs * 4096 + l * 8;
#pragma unroll
        for (int li = 0; li < 4; ++li) {
            __builtin_amdgcn_global_load_lds(GLOBAL_AS(s + li * 512),
                                             LDS_AS(ldsb + li * 512), 16, 0, 0);
        }
        __syncthreads();

        f16x8 a_h[4], b_h[4];
#pragma unroll
        for (int mi = 0; mi < 4; ++mi) {
            const int dd = wd * 64 + mi * 16 + r;
            a_h[mi] = *(const f16x8*)&lds[0][(cg * 128 + dd) * 8];
        }
#pragma unroll
        for (int ni = 0; ni < 4; ++ni) {
            const int jj = wj * 64 + ni * 16 + r;
            b_h[ni] = *(const f16x8*)&lds[1][(cg * 128 + jj) * 8];
        }
#pragma unroll
        for (int mi = 0; mi < 4; ++mi)
#pragma unroll
            for (int ni = 0; ni < 4; ++ni)
                acc[mi][ni] = __builtin_amdgcn_mfma_f32_16x16x32_f16(
                    a_h[mi], b_h[ni], acc[mi][ni], 0, 0, 0);
        __syncthreads();
    }

    // Epilogue: partial[j] = sum_d tanh(acc + h1) * w2
    const int q4 = cg * 4;
    float w2v[4][4];
#pragma unroll
    for (int mi = 0; mi < 4; ++mi)
#pragma unroll
        for (int q = 0; q < 4; ++q)
            w2v[mi][q] = W2[dt * 128 + wd * 64 + mi * 16 + q4 + q];

    float partial[4];
#pragma unroll
    for (int ni = 0; ni < 4; ++ni) {
        const int jg = jt * 128 + wj * 64 + ni * 16 + r;
        const int bj = jg / N_;
        const float* h1p = h1 + (size_t)bj * HID_ + dt * 128 + wd * 64;
        float s = 0.f;
#pragma unroll
        for (int mi = 0; mi < 4; ++mi)
#pragma unroll
            for (int q = 0; q < 4; ++q)
                s += tanhf(acc[mi][ni][q] + h1p[mi * 16 + q4 + q]) * w2v[mi][q];
        partial[ni] = s;
    }

    float* red = (float*)&lds[0][0];
    if (tid < 128) red[tid] = 0.f;
    __syncthreads();
#pragma unroll
    for (int ni = 0; ni < 4; ++ni)
        atomicAdd(&red[wj * 64 + ni * 16 + r], partial[ni]);
    __syncthreads();
    if (tid < 128)
        ps[(size_t)dt * NJ_ + (size_t)jt * 128 + tid] = red[tid];
}

// ---------------------------------------------------------------------------
// K2 fallback (fp32 vector path) if workspace is too small for packing.
// ---------------------------------------------------------------------------
__global__ __launch_bounds__(256) void k2_fb(
    const float* __restrict__ spatial, const float* __restrict__ W1,
    const float* __restrict__ W2, const float* __restrict__ h1,
    float* __restrict__ ps)
{
    __shared__ float As[32][64];
    __shared__ float Bs[32][64];
    const int t = threadIdx.x;
    const int d0 = blockIdx.x * 64;
    const int j0 = blockIdx.y * 64;
    const int ld = t & 63, lk = t >> 6;
    const float* Aptr = W1 + (size_t)(HID_ + lk) * HID_ + (d0 + ld);
    const int j = j0 + ld;
    const int bb = j / N_, nn = j - bb * N_;
    const float* Bptr = spatial + (size_t)bb * SPB_ + (size_t)lk * N_ + nn;
    const int tr = t >> 4, tc = t & 15;
    float acc[4][4] = {};
    for (int c0 = 0; c0 < SP_; c0 += 32) {
#pragma unroll
        for (int i = 0; i < 8; ++i) {
            As[lk + 4 * i][ld] = Aptr[(size_t)(c0 + 4 * i) * HID_];
            Bs[lk + 4 * i][ld] = Bptr[(size_t)(c0 + 4 * i) * N_];
        }
        __syncthreads();
#pragma unroll
        for (int k = 0; k < 32; ++k) {
            float av[4], bv[4];
            *(float4*)av = *(const float4*)&As[k][tr * 4];
            *(float4*)bv = *(const float4*)&Bs[k][tc * 4];
#pragma unroll
            for (int di = 0; di < 4; ++di)
#pragma unroll
                for (int ji = 0; ji < 4; ++ji)
                    acc[di][ji] += av[di] * bv[ji];
        }
        __syncthreads();
    }
    float w2v[4];
#pragma unroll
    for (int di = 0; di < 4; ++di) w2v[di] = W2[d0 + tr * 4 + di];
    float partial[4] = {};
#pragma unroll
    for (int ji = 0; ji < 4; ++ji) {
        const int jg = j0 + tc * 4 + ji;
        const int bj = jg / N_;
        const float* h1row = h1 + (size_t)bj * HID_ + d0 + tr * 4;
#pragma unroll
        for (int di = 0; di < 4; ++di)
            partial[ji] += tanhf(acc[di][ji] + h1row[di]) * w2v[di];
    }
    __shared__ float red[64];
    if (t < 64) red[t] = 0.f;
    __syncthreads();
#pragma unroll
    for (int ji = 0; ji < 4; ++ji)
        atomicAdd(&red[tc * 4 + ji], partial[ji]);
    __syncthreads();
    if (t < 64)
        ps[(size_t)blockIdx.x * NJ_ + j0 + t] = red[t];
}

// ---------------------------------------------------------------------------
// K3: scores[b,n] = sum_slices ps; attn = softmax_n  (b2 shift-invariant)
// ---------------------------------------------------------------------------
__global__ __launch_bounds__(256) void k3_softmax(
    const float* __restrict__ ps, float* __restrict__ attn, int nslices)
{
    const int b = blockIdx.x;
    const int t = threadIdx.x;
    __shared__ float sdata[256];

    float s = -1e30f;
    if (t < N_) {
        s = 0.f;
        for (int dt = 0; dt < nslices; ++dt)
            s += ps[(size_t)dt * NJ_ + b * N_ + t];
    }
    sdata[t] = s;
    __syncthreads();
    for (int off = 128; off > 0; off >>= 1) {
        if (t < off) sdata[t] = fmaxf(sdata[t], sdata[t + off]);
        __syncthreads();
    }
    const float m = sdata[0];
    __syncthreads();
    const float e = (t < N_) ? expf(s - m) : 0.f;
    sdata[t] = e;
    __syncthreads();
    for (int off = 128; off > 0; off >>= 1) {
        if (t < off) sdata[t] += sdata[t + off];
        __syncthreads();
    }
    const float inv = 1.f / sdata[0];
    if (t < N_) attn[(size_t)b * N_ + t] = e * inv;
}

// ---------------------------------------------------------------------------
// K4: context[b,c] = sum_n attn[b,n] * spatial[b, c*196 + n]
// ---------------------------------------------------------------------------
__global__ __launch_bounds__(256) void k4_context(
    const float* __restrict__ spatial, const float* __restrict__ attn,
    float* __restrict__ ctx)
{
    const int wid = (blockIdx.x * 256 + threadIdx.x) >> 6;
    const int lane = threadIdx.x & 63;
    const int b = wid >> 11;
    const int c = wid & 2047;
    const float* sp = spatial + (size_t)b * SPB_ + (size_t)c * N_;
    const float* at = attn + (size_t)b * N_;

    float sum = 0.f;
    for (int n = lane; n < N_; n += 64)
        sum += at[n] * sp[n];
#pragma unroll
    for (int off = 32; off > 0; off >>= 1)
        sum += __shfl_down(sum, off, 64);
    if (lane == 0)
        ctx[(size_t)b * 2048 + c] = sum;
}

// ---------------------------------------------------------------------------
extern "C" void kernel_launch(void* const* d_in, const int* in_sizes, int n_in,
                              void* d_out, int out_size, void* d_ws, size_t ws_size,
                              hipStream_t stream)
{
    const float* hidden  = (const float*)d_in[0];
    const float* spatial = (const float*)d_in[1];
    const float* W1      = (const float*)d_in[2];
    const float* b1      = (const float*)d_in[3];
    const float* W2      = (const float*)d_in[4];
    // b2 unused: softmax shift-invariant.

    float* out_ctx  = (float*)d_out;
    float* out_attn = (float*)d_out + (size_t)B_ * 2048;

    char* ws = (char*)d_ws;
    float* h1 = (float*)ws;                               // 1 MB
    float* psb = (float*)(ws + (1u << 20));               // up to 16 slices (3.2 MB)

    // MFMA-path workspace layout (fp16, hi-only)
    const size_t offAh = 8u << 20;                         // 4 MB
    const size_t offBh = 16u << 20;                        // 196 MB
    const size_t szB   = (size_t)392 * 64 * 4096 * 2;      // 205,520,896 B
    const size_t needed = offBh + szB;                     // ~212 MB

    k1_h1<<<dim3(4, 32), 256, 0, stream>>>(hidden, W1, b1, h1);

    if (ws_size >= needed) {
        __half* Ah = (__half*)(ws + offAh);
        __half* Bh = (__half*)(ws + offBh);

        k0a_packA<<<dim3(8192), 256, 0, stream>>>(W1, Ah);
        k0b_packB<<<dim3(392, 64), 256, 0, stream>>>(spatial, Bh);
        k2_mfma<<<dim3(3136), 256, 0, stream>>>(Ah, Bh, W2, h1, psb);
        k3_softmax<<<dim3(B_), 256, 0, stream>>>(psb, out_attn, 8);
    } else {
        k2_fb<<<dim3(16, 784), 256, 0, stream>>>(spatial, W1, W2, h1, psb);
        k3_softmax<<<dim3(B_), 256, 0, stream>>>(psb, out_attn, 16);
    }
    k4_context<<<dim3((B_ * 2048) / 4), 256, 0, stream>>>(spatial, out_attn, out_ctx);
}

// Round 4
// 609.761 us; speedup vs baseline: 4.9894x; 1.1657x over previous
//
#include <hip/hip_runtime.h>
#include <hip/hip_bf16.h>
#include <hip/hip_fp16.h>
#include <math.h>

// Problem constants
#define B_   256
#define HID_ 1024
#define SP_  2048
#define N_   196        // 14*14
#define NJ_  (B_ * N_)  // 50176 = 392 * 128
#define SPB_ (SP_ * N_) // elems per batch of spatial

typedef float    f32x4 __attribute__((ext_vector_type(4)));
typedef _Float16 f16x8 __attribute__((ext_vector_type(8)));

#define GLOBAL_AS(p) ((const __attribute__((address_space(1))) void*)(p))
#define LDS_AS(p)    ((__attribute__((address_space(3))) void*)(p))

// ---------------------------------------------------------------------------
// K1: h1[b,d] = hidden @ W1h + b1   (256x1024 @ 1024x1024)
// ---------------------------------------------------------------------------
__global__ __launch_bounds__(256) void k1_h1(
    const float* __restrict__ hidden, const float* __restrict__ W1,
    const float* __restrict__ b1, float* __restrict__ h1)
{
    __shared__ float hs[8][HID_];
    const int t = threadIdx.x;
    const int d = blockIdx.x * 256 + t;
    const int b0 = blockIdx.y * 8;

    for (int i = t; i < 8 * HID_; i += 256)
        hs[i >> 10][i & 1023] = hidden[(size_t)(b0 + (i >> 10)) * HID_ + (i & 1023)];
    __syncthreads();

    float acc[8] = {};
    for (int h = 0; h < HID_; ++h) {
        const float w = W1[(size_t)h * HID_ + d];
#pragma unroll
        for (int i = 0; i < 8; ++i) acc[i] += hs[i][h] * w;
    }
    const float bias = b1[d];
#pragma unroll
    for (int i = 0; i < 8; ++i)
        h1[(size_t)(b0 + i) * HID_ + d] = acc[i] + bias;
}

// ---------------------------------------------------------------------------
// K0a: pack A = W1s^T (d x c, 1024x2048) into fp16 tiles.
// Tile (dt, cs): 128 d x 32 c, layout [cg(4)][dd(128)][c8(8)], 4096 elems.
// ---------------------------------------------------------------------------
__global__ __launch_bounds__(256) void k0a_packA(
    const float* __restrict__ W1, __half* __restrict__ Ah)
{
    const size_t idx = (size_t)blockIdx.x * 256 + threadIdx.x;  // < 2,097,152
    const int dt = idx >> 18;
    const int cs = (idx >> 12) & 63;
    const int e  = idx & 4095;
    const int cg = e >> 10, dd = (e >> 3) & 127, c8 = e & 7;
    const int d = dt * 128 + dd;
    const int c = cs * 32 + cg * 8 + c8;
    Ah[idx] = __float2half(W1[(size_t)(HID_ + c) * HID_ + d]);
}

// ---------------------------------------------------------------------------
// K2 (MFMA): C[d,j] = A·B single-pass fp16; B reg-staged DIRECTLY from
// fp32 spatial (no pack kernel): global->reg->cvt->ds_write_b128.
//   partial_score[dt, j] = sum_{d in tile} tanh(C + h1[bj,d]) * w2[d]
// 128x128 tile, BK=32, 4 waves (2d x 2j), 16x16x32 MFMA f16, 4x4 frags/wave.
// ---------------------------------------------------------------------------
__global__ __launch_bounds__(256, 2) void k2_mfma(
    const __half* __restrict__ Ah, const float* __restrict__ spatial,
    const float* __restrict__ W2, const float* __restrict__ h1,
    float* __restrict__ ps)
{
    __shared__ __align__(16) short lds[2][4096];  // [0]=A, [1]=B (8 KB each)

    const int tid = threadIdx.x;
    const int l = tid & 63;
    const int w = tid >> 6;           // wave 0..3
    const int wd = w >> 1, wj = w & 1;
    const int cg = l >> 4, r = l & 15;

    // XCD-chunked swizzle: 3136 blocks, 8 XCDs, dt fastest -> same jt's
    // spatial panel (1 MB) is reused 8x through the XCD's L2.
    const int f = blockIdx.x;
    const int xcd = f & 7, p = f >> 3;
    const int dt = p & 7;               // 0..7
    const int jt = xcd * 49 + (p >> 3); // 0..391

    // ---- B direct staging mapping: thread owns column jj, half the c's ----
    const int jj = tid & 127;
    const int chalf = tid >> 7;         // 0/1 -> c = cs*32 + chalf*16 + k
    {
    }
    const int jg0 = jt * 128 + jj;
    const int bb0 = jg0 / N_;
    const int nn0 = jg0 - bb0 * N_;
    const float* bsrc = spatial + (size_t)bb0 * SPB_ + nn0 + (size_t)(chalf * 16) * N_;
    // value for c -> lds[1] layout [cg(4)][jj(128)][c8(8)], cg=chalf*2+(k>>3), c8=k&7
    short* bdst0 = &lds[1][((chalf * 2 + 0) * 128 + jj) * 8];
    short* bdst1 = &lds[1][((chalf * 2 + 1) * 128 + jj) * 8];

    f32x4 acc[4][4] = {};

    for (int cs = 0; cs < 64; ++cs) {
        // 1) issue B global loads (fp32 -> regs)
        const float* bs = bsrc + (size_t)cs * 32 * N_;
        float bv[16];
#pragma unroll
        for (int k = 0; k < 16; ++k) bv[k] = bs[(size_t)k * N_];

        // 2) A tile: linear async copy (8 KB), 2 x 1KB per wave
        {
            const __half* as = Ah + ((size_t)dt * 64 + cs) * 4096;
            __builtin_amdgcn_global_load_lds(GLOBAL_AS(as + (size_t)(w * 64 + l) * 8),
                                             LDS_AS(&lds[0][(w * 64) * 8]), 16, 0, 0);
            __builtin_amdgcn_global_load_lds(GLOBAL_AS(as + (size_t)(256 + w * 64 + l) * 8),
                                             LDS_AS(&lds[0][(256 + w * 64) * 8]), 16, 0, 0);
        }

        // 3) convert B to fp16 and ds_write (prev compute finished at loop-end barrier)
        f16x8 h0, h1v;
#pragma unroll
        for (int k = 0; k < 8; ++k) {
            h0[k]  = (_Float16)bv[k];
            h1v[k] = (_Float16)bv[k + 8];
        }
        *(f16x8*)bdst0 = h0;
        *(f16x8*)bdst1 = h1v;

        __syncthreads();   // drains gload_lds (vmcnt) + ds_write (lgkmcnt)

        // 4) fragments + MFMA
        f16x8 a_h[4], b_h[4];
#pragma unroll
        for (int mi = 0; mi < 4; ++mi) {
            const int dd = wd * 64 + mi * 16 + r;
            a_h[mi] = *(const f16x8*)&lds[0][(cg * 128 + dd) * 8];
        }
#pragma unroll
        for (int ni = 0; ni < 4; ++ni) {
            const int jjf = wj * 64 + ni * 16 + r;
            b_h[ni] = *(const f16x8*)&lds[1][(cg * 128 + jjf) * 8];
        }
#pragma unroll
        for (int mi = 0; mi < 4; ++mi)
#pragma unroll
            for (int ni = 0; ni < 4; ++ni)
                acc[mi][ni] = __builtin_amdgcn_mfma_f32_16x16x32_f16(
                    a_h[mi], b_h[ni], acc[mi][ni], 0, 0, 0);
        __syncthreads();
    }

    // Epilogue: partial[j] = sum_d tanh(acc + h1) * w2
    const int q4 = cg * 4;
    float w2v[4][4];
#pragma unroll
    for (int mi = 0; mi < 4; ++mi)
#pragma unroll
        for (int q = 0; q < 4; ++q)
            w2v[mi][q] = W2[dt * 128 + wd * 64 + mi * 16 + q4 + q];

    float partial[4];
#pragma unroll
    for (int ni = 0; ni < 4; ++ni) {
        const int jge = jt * 128 + wj * 64 + ni * 16 + r;
        const int bj = jge / N_;
        const float* h1p = h1 + (size_t)bj * HID_ + dt * 128 + wd * 64;
        float s = 0.f;
#pragma unroll
        for (int mi = 0; mi < 4; ++mi)
#pragma unroll
            for (int q = 0; q < 4; ++q)
                s += tanhf(acc[mi][ni][q] + h1p[mi * 16 + q4 + q]) * w2v[mi][q];
        partial[ni] = s;
    }

    float* red = (float*)&lds[0][0];
    if (tid < 128) red[tid] = 0.f;
    __syncthreads();
#pragma unroll
    for (int ni = 0; ni < 4; ++ni)
        atomicAdd(&red[wj * 64 + ni * 16 + r], partial[ni]);
    __syncthreads();
    if (tid < 128)
        ps[(size_t)dt * NJ_ + (size_t)jt * 128 + tid] = red[tid];
}

// ---------------------------------------------------------------------------
// K2 fallback (fp32 vector path) if workspace is too small for packing.
// ---------------------------------------------------------------------------
__global__ __launch_bounds__(256) void k2_fb(
    const float* __restrict__ spatial, const float* __restrict__ W1,
    const float* __restrict__ W2, const float* __restrict__ h1,
    float* __restrict__ ps)
{
    __shared__ float As[32][64];
    __shared__ float Bs[32][64];
    const int t = threadIdx.x;
    const int d0 = blockIdx.x * 64;
    const int j0 = blockIdx.y * 64;
    const int ld = t & 63, lk = t >> 6;
    const float* Aptr = W1 + (size_t)(HID_ + lk) * HID_ + (d0 + ld);
    const int j = j0 + ld;
    const int bb = j / N_, nn = j - bb * N_;
    const float* Bptr = spatial + (size_t)bb * SPB_ + (size_t)lk * N_ + nn;
    const int tr = t >> 4, tc = t & 15;
    float acc[4][4] = {};
    for (int c0 = 0; c0 < SP_; c0 += 32) {
#pragma unroll
        for (int i = 0; i < 8; ++i) {
            As[lk + 4 * i][ld] = Aptr[(size_t)(c0 + 4 * i) * HID_];
            Bs[lk + 4 * i][ld] = Bptr[(size_t)(c0 + 4 * i) * N_];
        }
        __syncthreads();
#pragma unroll
        for (int k = 0; k < 32; ++k) {
            float av[4], bv[4];
            *(float4*)av = *(const float4*)&As[k][tr * 4];
            *(float4*)bv = *(const float4*)&Bs[k][tc * 4];
#pragma unroll
            for (int di = 0; di < 4; ++di)
#pragma unroll
                for (int ji = 0; ji < 4; ++ji)
                    acc[di][ji] += av[di] * bv[ji];
        }
        __syncthreads();
    }
    float w2v[4];
#pragma unroll
    for (int di = 0; di < 4; ++di) w2v[di] = W2[d0 + tr * 4 + di];
    float partial[4] = {};
#pragma unroll
    for (int ji = 0; ji < 4; ++ji) {
        const int jg = j0 + tc * 4 + ji;
        const int bj = jg / N_;
        const float* h1row = h1 + (size_t)bj * HID_ + d0 + tr * 4;
#pragma unroll
        for (int di = 0; di < 4; ++di)
            partial[ji] += tanhf(acc[di][ji] + h1row[di]) * w2v[di];
    }
    __shared__ float red[64];
    if (t < 64) red[t] = 0.f;
    __syncthreads();
#pragma unroll
    for (int ji = 0; ji < 4; ++ji)
        atomicAdd(&red[tc * 4 + ji], partial[ji]);
    __syncthreads();
    if (t < 64)
        ps[(size_t)blockIdx.x * NJ_ + j0 + t] = red[t];
}

// ---------------------------------------------------------------------------
// K3: scores[b,n] = sum_slices ps; attn = softmax_n  (b2 shift-invariant)
// ---------------------------------------------------------------------------
__global__ __launch_bounds__(256) void k3_softmax(
    const float* __restrict__ ps, float* __restrict__ attn, int nslices)
{
    const int b = blockIdx.x;
    const int t = threadIdx.x;
    __shared__ float sdata[256];

    float s = -1e30f;
    if (t < N_) {
        s = 0.f;
        for (int dt = 0; dt < nslices; ++dt)
            s += ps[(size_t)dt * NJ_ + b * N_ + t];
    }
    sdata[t] = s;
    __syncthreads();
    for (int off = 128; off > 0; off >>= 1) {
        if (t < off) sdata[t] = fmaxf(sdata[t], sdata[t + off]);
        __syncthreads();
    }
    const float m = sdata[0];
    __syncthreads();
    const float e = (t < N_) ? expf(s - m) : 0.f;
    sdata[t] = e;
    __syncthreads();
    for (int off = 128; off > 0; off >>= 1) {
        if (t < off) sdata[t] += sdata[t + off];
        __syncthreads();
    }
    const float inv = 1.f / sdata[0];
    if (t < N_) attn[(size_t)b * N_ + t] = e * inv;
}

// ---------------------------------------------------------------------------
// K4: context[b,c] = sum_n attn[b,n] * spatial[b, c*196 + n]
// 196 = 49 float4 (row base 784 B, 16B-aligned). One wave per (b,c).
// ---------------------------------------------------------------------------
__global__ __launch_bounds__(256) void k4_context(
    const float* __restrict__ spatial, const float* __restrict__ attn,
    float* __restrict__ ctx)
{
    const int wid = (blockIdx.x * 256 + threadIdx.x) >> 6;
    const int lane = threadIdx.x & 63;
    const int b = wid >> 11;
    const int c = wid & 2047;
    const float* sp = spatial + (size_t)b * SPB_ + (size_t)c * N_;
    const float* at = attn + (size_t)b * N_;

    float sum = 0.f;
    if (lane < 49) {
        const float4 s4 = ((const float4*)sp)[lane];
        const float4 a4 = ((const float4*)at)[lane];
        sum = s4.x * a4.x + s4.y * a4.y + s4.z * a4.z + s4.w * a4.w;
    }
#pragma unroll
    for (int off = 32; off > 0; off >>= 1)
        sum += __shfl_down(sum, off, 64);
    if (lane == 0)
        ctx[(size_t)b * 2048 + c] = sum;
}

// ---------------------------------------------------------------------------
extern "C" void kernel_launch(void* const* d_in, const int* in_sizes, int n_in,
                              void* d_out, int out_size, void* d_ws, size_t ws_size,
                              hipStream_t stream)
{
    const float* hidden  = (const float*)d_in[0];
    const float* spatial = (const float*)d_in[1];
    const float* W1      = (const float*)d_in[2];
    const float* b1      = (const float*)d_in[3];
    const float* W2      = (const float*)d_in[4];
    // b2 unused: softmax shift-invariant.

    float* out_ctx  = (float*)d_out;
    float* out_attn = (float*)d_out + (size_t)B_ * 2048;

    char* ws = (char*)d_ws;
    float* h1 = (float*)ws;                               // 1 MB
    float* psb = (float*)(ws + (1u << 20));               // up to 16 slices (3.2 MB)

    // MFMA-path workspace layout (A pack only, ~4 MB)
    const size_t offAh  = 8u << 20;
    const size_t needed = offAh + ((size_t)8 * 64 * 4096 * 2);  // ~12 MB

    k1_h1<<<dim3(4, 32), 256, 0, stream>>>(hidden, W1, b1, h1);

    if (ws_size >= needed) {
        __half* Ah = (__half*)(ws + offAh);
        k0a_packA<<<dim3(8192), 256, 0, stream>>>(W1, Ah);
        k2_mfma<<<dim3(3136), 256, 0, stream>>>(Ah, spatial, W2, h1, psb);
        k3_softmax<<<dim3(B_), 256, 0, stream>>>(psb, out_attn, 8);
    } else {
        k2_fb<<<dim3(16, 784), 256, 0, stream>>>(spatial, W1, W2, h1, psb);
        k3_softmax<<<dim3(B_), 256, 0, stream>>>(psb, out_attn, 16);
    }
    k4_context<<<dim3((B_ * 2048) / 4), 256, 0, stream>>>(spatial, out_attn, out_ctx);
}